// Round 6
// baseline (22.099 us; speedup 1.0000x reference)
//
#include <hip/hip_runtime.h>
#include <math.h>

#define S 26
#define A 5
#define C 80
#define B 64
#define T 16
#define DSR 32.0f
#define N_CELLS (S * S)          // 676
#define N_PRED (S * S * A)       // 3380
#define CONF_N (B * N_PRED)      // 216320
#define CONF_N4 (CONF_N / 4)     // 54080 (exact; % 64 == 0 -> wave aligned)
#define NBT (B * T)              // 1024
#define BS 1024
#define NBLK 54                  // 54*1024 = 55296 >= CONF_N4 + NBT = 55104
#define PSTRIDE 64               // partials stride (padded)
#define NWAVE (BS / 64)          // 16

// Per-thread work, exactly one job per thread (verified absmax 0.0 in R4):
//  gidx <  CONF_N4            : one float4 of conf^2
//  gidx in [CONF_N4, +NBT)    : one (b,t) assignment (whole waves -> shuffles)
__device__ __forceinline__ void compute_terms(
        int gidx,
        const float* __restrict__ conf,
        const float* __restrict__ pred_xy,
        const float* __restrict__ pred_wh,
        const float* __restrict__ cls_score,
        const float* __restrict__ true_object,
        const float* __restrict__ true_label,
        const float* __restrict__ anchors,
        float vs[6]) {
    vs[0] = vs[1] = vs[2] = vs[3] = vs[4] = vs[5] = 0.f;

    if (gidx < CONF_N4) {
        float4 c = ((const float4*)conf)[gidx];
        vs[0] = c.x * c.x + c.y * c.y + c.z * c.z + c.w * c.w;
    } else if (gidx < CONF_N4 + NBT) {
        const int bt = gidx - CONF_N4;
        const int b = bt >> 4;
        const int t = bt & 15;
        const int lane = gidx & 63;      // == bt & 63 since CONF_N4 % 64 == 0

        float4 to = ((const float4*)true_object)[bt];
        float gx = to.x / DSR, gy = to.y / DSR;
        float gw = to.z / DSR, gh = to.w / DSR;
        int i = min(max((int)floorf(gx), 0), S - 1);
        int j = min(max((int)floorf(gy), 0), S - 1);
        int ij = i * S + j;

        // winner = no later box of this image in the same cell (last write wins)
        // image b's 16 boxes sit in one 16-lane group -> pure shuffles
        bool winner = true;
        #pragma unroll
        for (int t2 = 0; t2 < T; ++t2) {
            int ij2 = __shfl(ij, (lane & 48) + t2, 64);
            if (t2 > t && ij2 == ij) winner = false;
        }

        if (winner) {
            float iou_a[A];
            int best = 0;
            float bestv = -1.f;
            #pragma unroll
            for (int a = 0; a < A; ++a) {
                float aw = anchors[a * 2 + 0], ah = anchors[a * 2 + 1];
                float inter = fminf(gw, aw) * fminf(gh, ah);
                float uni = gw * gh + aw * ah - inter;
                float val = inter / uni;
                iou_a[a] = val;
                if (val > bestv) { bestv = val; best = a; }
            }

            size_t base = (size_t)b * N_PRED + (size_t)ij * A;

            #pragma unroll
            for (int a = 0; a < A; ++a) {
                if (a == best || iou_a[a] > 0.5f) {
                    float c = conf[base + a];
                    vs[1] += 0.5f * c * c;
                }
            }

            float2 pwh = ((const float2*)pred_wh)[base + best];
            float pw = pwh.x, ph = pwh.y;
            float inter = fminf(pw, gw) * fminf(ph, gh);
            float uni = pw * ph + gw * gh - inter;
            float iou_pg = inter / uni;
            float cbest = conf[base + best];
            float d = cbest - iou_pg;
            vs[2] = 0.5f * d * d;

            float sw = 2.0f - (gw / (float)S) * (gh / (float)S);
            if (sw > 0.f) {
                // fm quirk: fm[n] = fm_cord[n mod 676], n = (i*S+j)*A + best
                int n = ij * A + best;
                int p = n % N_CELLS;
                float fm0 = (float)(p / S);
                float fm1 = (float)(p % S);
                float2 pxy = ((const float2*)pred_xy)[base + best];
                float x0 = pxy.x - fm0, tt0 = gx - fm0;
                float x1 = pxy.y - fm1, tt1 = gy - fm1;
                float bce0 = fmaxf(x0, 0.f) - x0 * tt0 + log1pf(expf(-fabsf(x0)));
                float bce1 = fmaxf(x1, 0.f) - x1 * tt1 + log1pf(expf(-fabsf(x1)));
                vs[3] = sw * (bce0 + bce1);
                float dw = pw - gw, dh = ph - gh;
                vs[4] = sw * (dw * dw + dh * dh);

                const float4* cs4 = (const float4*)(cls_score + (base + best) * C);
                const float4* tl4 = (const float4*)(true_label + (size_t)bt * C);
                float sacc = 0.f;
                #pragma unroll
                for (int c4 = 0; c4 < C / 4; ++c4) {
                    float4 cc = cs4[c4];
                    float4 tl = tl4[c4];
                    float d0 = cc.x - tl.x, d1 = cc.y - tl.y;
                    float d2 = cc.z - tl.z, d3 = cc.w - tl.w;
                    sacc += d0 * d0 + d1 * d1 + d2 * d2 + d3 * d3;
                }
                vs[5] = sacc;
            }
        }
    }
}

// ---------------- Kernel 1: compute + block reduce (1 barrier) -----------
// partials[k * PSTRIDE + bid], k = 0..5
__global__ __launch_bounds__(BS) void main_kernel(
        const float* __restrict__ conf, const float* __restrict__ pred_xy,
        const float* __restrict__ pred_wh, const float* __restrict__ cls_score,
        const float* __restrict__ true_object, const float* __restrict__ true_label,
        const float* __restrict__ anchors, float* __restrict__ partials) {
    const int tid = threadIdx.x;
    const int bid = blockIdx.x;
    float vs[6];
    compute_terms(bid * BS + tid, conf, pred_xy, pred_wh, cls_score,
                  true_object, true_label, anchors, vs);

    #pragma unroll
    for (int k = 0; k < 6; ++k) {
        float v = vs[k];
        #pragma unroll
        for (int off = 32; off >= 1; off >>= 1)
            v += __shfl_xor(v, off, 64);
        vs[k] = v;   // lane-uniform within wave
    }
    __shared__ float sm[NWAVE * 6];
    const int wave = tid >> 6;
    const int lane = tid & 63;
    if (lane == 0) {
        #pragma unroll
        for (int k = 0; k < 6; ++k) sm[wave * 6 + k] = vs[k];
    }
    __syncthreads();
    if (tid < 6) {
        float s = 0.f;
        #pragma unroll
        for (int w = 0; w < NWAVE; ++w) s += sm[w * 6 + tid];
        partials[tid * PSTRIDE + bid] = s;
    }
}

// ---------------- Kernel 2: finalize (single wave, no barriers) ----------
__global__ __launch_bounds__(64) void finalize_kernel(
        const float* __restrict__ partials, float* __restrict__ out) {
    const int tid = threadIdx.x;  // 0..63
    float sums[6];
    #pragma unroll
    for (int k = 0; k < 6; ++k) {
        float v = (tid < NBLK) ? partials[k * PSTRIDE + tid] : 0.f;
        #pragma unroll
        for (int off = 32; off >= 1; off >>= 1)
            v += __shfl_xor(v, off, 64);
        sums[k] = v;
    }
    if (tid == 0) {
        const float invB = 1.0f / (float)B;
        float noobj = (0.5f * sums[0] - sums[1]) * invB;   // SCALE_NOOBJ = 1
        float obj   = 5.0f * sums[2] * invB;               // 0.5 already applied
        float xy    = 2.5f * sums[3] * invB;
        float wh    = 2.5f * sums[4] * invB;
        float score = 2.5f * sums[5] * invB;
        out[0] = score;          // total_loss (overwritten by score_loss in ref)
        out[1] = noobj * 0.25f;
        out[2] = obj * 0.25f;
        out[3] = score * 0.25f;
        out[4] = xy * 0.25f;
        out[5] = wh * 0.25f;
    }
}

extern "C" void kernel_launch(void* const* d_in, const int* in_sizes, int n_in,
                              void* d_out, int out_size, void* d_ws, size_t ws_size,
                              hipStream_t stream) {
    // setup_inputs order:
    // 0: epoch (unused), 1: conf, 2: pred_xy, 3: pred_wh, 4: cls_score,
    // 5: true_object, 6: true_label, 7: fm_cord (recomputed), 8: anchors
    const float* conf        = (const float*)d_in[1];
    const float* pred_xy     = (const float*)d_in[2];
    const float* pred_wh     = (const float*)d_in[3];
    const float* cls_score   = (const float*)d_in[4];
    const float* true_object = (const float*)d_in[5];
    const float* true_label  = (const float*)d_in[6];
    const float* anchors     = (const float*)d_in[8];

    float* ws  = (float*)d_ws;   // partials: 6 * PSTRIDE floats
    float* out = (float*)d_out;

    hipLaunchKernelGGL(main_kernel, dim3(NBLK), dim3(BS), 0, stream,
                       conf, pred_xy, pred_wh, cls_score, true_object,
                       true_label, anchors, ws);
    hipLaunchKernelGGL(finalize_kernel, dim3(1), dim3(64), 0, stream, ws, out);
}

// Round 7
// 13.161 us; speedup vs baseline: 1.6791x; 1.6791x over previous
//
#include <hip/hip_runtime.h>
#include <math.h>

#define S 26
#define A 5
#define C 80
#define B 64
#define T 16
#define DSR 32.0f
#define N_CELLS (S * S)          // 676
#define N_PRED (S * S * A)       // 3380
#define CONF_N (B * N_PRED)      // 216320
#define CONF_N4 (CONF_N / 4)     // 54080 (exact)
#define NBT (B * T)              // 1024
#define NBLK 256
#define BS 256
#define NWAVE (BS / 64)          // 4

// ---------------- Kernel 1: compute + block reduce (R3 geometry) ---------
// Blocks 0..3 double duty: threads do one conf float4 AND one assignment.
// partials[k * NBLK + bid], k = 0..5
//   k=0: sum conf^2
//   k=1: noobj correction   k=2: obj term
//   k=3: xy term            k=4: wh term        k=5: cls term
__global__ __launch_bounds__(BS) void main_kernel(
        const float* __restrict__ conf,
        const float* __restrict__ pred_xy,
        const float* __restrict__ pred_wh,
        const float* __restrict__ cls_score,
        const float* __restrict__ true_object,
        const float* __restrict__ true_label,
        const float* __restrict__ anchors,
        float* __restrict__ partials) {
    const int tid = threadIdx.x;
    const int bid = blockIdx.x;
    const int gidx = bid * BS + tid;
    const int lane = tid & 63;
    const int wave = tid >> 6;

    float v0 = 0.f, v1 = 0.f, v2 = 0.f, v3 = 0.f, v4 = 0.f, v5 = 0.f;

    // ---- bulk: one float4 of conf^2 per thread (54080 of 65536 threads) ----
    if (gidx < CONF_N4) {
        float4 c = ((const float4*)conf)[gidx];
        v0 = c.x * c.x + c.y * c.y + c.z * c.z + c.w * c.w;
    }

    // ---- sparse: one (b,t) assignment per thread of blocks 0..3 ----------
    if (gidx < NBT) {
        const int bt = gidx;
        const int b = bt >> 4;
        const int t = bt & 15;

        float4 to = ((const float4*)true_object)[bt];
        float gx = to.x / DSR, gy = to.y / DSR;
        float gw = to.z / DSR, gh = to.w / DSR;
        int i = min(max((int)floorf(gx), 0), S - 1);
        int j = min(max((int)floorf(gy), 0), S - 1);
        int ij = i * S + j;

        // winner = no later box of this image in the same cell (last write wins)
        // image b's 16 boxes sit in one 16-lane group -> pure shuffles on ij
        bool winner = true;
        #pragma unroll
        for (int t2 = 0; t2 < T; ++t2) {
            int ij2 = __shfl(ij, (lane & 48) + t2, 64);
            if (t2 > t && ij2 == ij) winner = false;
        }

        if (winner) {
            float iou_a[A];
            int best = 0;
            float bestv = -1.f;
            #pragma unroll
            for (int a = 0; a < A; ++a) {
                float aw = anchors[a * 2 + 0], ah = anchors[a * 2 + 1];
                float inter = fminf(gw, aw) * fminf(gh, ah);
                float uni = gw * gh + aw * ah - inter;
                float val = inter / uni;
                iou_a[a] = val;
                if (val > bestv) { bestv = val; best = a; }
            }

            size_t base = (size_t)b * N_PRED + (size_t)ij * A;

            #pragma unroll
            for (int a = 0; a < A; ++a) {
                if (a == best || iou_a[a] > 0.5f) {
                    float c = conf[base + a];
                    v1 += 0.5f * c * c;
                }
            }

            float2 pwh = ((const float2*)pred_wh)[base + best];
            float pw = pwh.x, ph = pwh.y;
            float inter = fminf(pw, gw) * fminf(ph, gh);
            float uni = pw * ph + gw * gh - inter;
            float iou_pg = inter / uni;
            float cbest = conf[base + best];
            float d = cbest - iou_pg;
            v2 = 0.5f * d * d;

            float sw = 2.0f - (gw / (float)S) * (gh / (float)S);
            if (sw > 0.f) {
                // fm quirk: fm[n] = fm_cord[n mod 676], n = (i*S+j)*A + best
                int n = ij * A + best;
                int p = n % N_CELLS;
                float fm0 = (float)(p / S);
                float fm1 = (float)(p % S);
                float2 pxy = ((const float2*)pred_xy)[base + best];
                float x0 = pxy.x - fm0, tt0 = gx - fm0;
                float x1 = pxy.y - fm1, tt1 = gy - fm1;
                float bce0 = fmaxf(x0, 0.f) - x0 * tt0 + log1pf(expf(-fabsf(x0)));
                float bce1 = fmaxf(x1, 0.f) - x1 * tt1 + log1pf(expf(-fabsf(x1)));
                v3 = sw * (bce0 + bce1);
                float dw = pw - gw, dh = ph - gh;
                v4 = sw * (dw * dw + dh * dh);

                const float4* cs4 = (const float4*)(cls_score + (base + best) * C);
                const float4* tl4 = (const float4*)(true_label + (size_t)bt * C);
                float sacc = 0.f;
                #pragma unroll
                for (int c4 = 0; c4 < C / 4; ++c4) {
                    float4 cc = cs4[c4];
                    float4 tl = tl4[c4];
                    float d0 = cc.x - tl.x, d1 = cc.y - tl.y;
                    float d2 = cc.z - tl.z, d3 = cc.w - tl.w;
                    sacc += d0 * d0 + d1 * d1 + d2 * d2 + d3 * d3;
                }
                v5 = sacc;
            }
        }
    }

    // ---- block reduce: wave shuffle butterflies, then one barrier ----
    float vs[6] = {v0, v1, v2, v3, v4, v5};
    #pragma unroll
    for (int k = 0; k < 6; ++k) {
        float v = vs[k];
        #pragma unroll
        for (int off = 32; off >= 1; off >>= 1)
            v += __shfl_xor(v, off, 64);
        vs[k] = v;   // lane-uniform within wave
    }
    __shared__ float sm[NWAVE * 6];
    if (lane == 0) {
        #pragma unroll
        for (int k = 0; k < 6; ++k) sm[wave * 6 + k] = vs[k];
    }
    __syncthreads();
    if (tid < 6) {
        float s = 0.f;
        #pragma unroll
        for (int w = 0; w < NWAVE; ++w) s += sm[w * 6 + tid];
        partials[tid * NBLK + bid] = s;
    }
}

// ---------------- Kernel 2: finalize (single wave, no barriers) ----------
__global__ __launch_bounds__(64) void finalize_kernel(
        const float* __restrict__ partials, float* __restrict__ out) {
    const int tid = threadIdx.x;  // 0..63
    float sums[6];
    #pragma unroll
    for (int k = 0; k < 6; ++k) {
        const float* p = partials + k * NBLK;
        float v = p[tid] + p[tid + 64] + p[tid + 128] + p[tid + 192];
        #pragma unroll
        for (int off = 32; off >= 1; off >>= 1)
            v += __shfl_xor(v, off, 64);
        sums[k] = v;
    }
    if (tid == 0) {
        const float invB = 1.0f / (float)B;
        float noobj = (0.5f * sums[0] - sums[1]) * invB;   // SCALE_NOOBJ = 1
        float obj   = 5.0f * sums[2] * invB;               // 0.5 already applied
        float xy    = 2.5f * sums[3] * invB;
        float wh    = 2.5f * sums[4] * invB;
        float score = 2.5f * sums[5] * invB;
        out[0] = score;          // total_loss (overwritten by score_loss in ref)
        out[1] = noobj * 0.25f;
        out[2] = obj * 0.25f;
        out[3] = score * 0.25f;
        out[4] = xy * 0.25f;
        out[5] = wh * 0.25f;
    }
}

extern "C" void kernel_launch(void* const* d_in, const int* in_sizes, int n_in,
                              void* d_out, int out_size, void* d_ws, size_t ws_size,
                              hipStream_t stream) {
    // setup_inputs order:
    // 0: epoch (unused), 1: conf, 2: pred_xy, 3: pred_wh, 4: cls_score,
    // 5: true_object, 6: true_label, 7: fm_cord (recomputed), 8: anchors
    const float* conf        = (const float*)d_in[1];
    const float* pred_xy     = (const float*)d_in[2];
    const float* pred_wh     = (const float*)d_in[3];
    const float* cls_score   = (const float*)d_in[4];
    const float* true_object = (const float*)d_in[5];
    const float* true_label  = (const float*)d_in[6];
    const float* anchors     = (const float*)d_in[8];

    float* ws  = (float*)d_ws;   // partials: 6 * NBLK floats
    float* out = (float*)d_out;

    hipLaunchKernelGGL(main_kernel, dim3(NBLK), dim3(BS), 0, stream,
                       conf, pred_xy, pred_wh, cls_score, true_object,
                       true_label, anchors, ws);
    hipLaunchKernelGGL(finalize_kernel, dim3(1), dim3(64), 0, stream, ws, out);
}